// Round 1
// 1376.240 us; speedup vs baseline: 1.3129x; 1.3129x over previous
//
#include <hip/hip_runtime.h>
#include <math.h>

// Problem constants
#define QTOT   512
#define CDIM   256
#define HDIM   1024
#define NROWS  500000
#define NB     128
#define NTILES ((NROWS + NB - 1) / NB)   // 3907
#define LDB    264                       // bf16 row stride in LDS (k_gemm only)
#define DELTA  2.0f

typedef short bf16x8 __attribute__((ext_vector_type(8)));
typedef float f32x4  __attribute__((ext_vector_type(4)));

__device__ __forceinline__ unsigned short bf16_rne(float f) {
  unsigned u = __float_as_uint(f);
  u += 0x7FFFu + ((u >> 16) & 1u);
  return (unsigned short)(u >> 16);
}
__device__ __forceinline__ unsigned bfp2(float a, float b) {
  return (unsigned)bf16_rne(a) | ((unsigned)bf16_rne(b) << 16);
}

// ---------------------------------------------------------------- K0: codes -> bf16(-2c), MFMA-frag swizzled
// frag layout: [qb(4)][m(8)][ks(8)][lane(64)][8 bf16]; lane = quad*16 + l15
// lane l of frag (qb,m,ks) holds A[q = qb*128 + m*16 + (l&15)][k = ks*32 + (l>>4)*8 + off]
__global__ void k_prep(const float* __restrict__ codes, unsigned short* __restrict__ a0s) {
  int q = blockIdx.x, k = threadIdx.x;
  float v = -2.0f * codes[q * CDIM + k];
  int qb = q >> 7, row = q & 127, m = row >> 4, l15 = row & 15;
  int ks = k >> 5, kin = k & 31, quad = kin >> 3, off = kin & 7;
  int lane = quad * 16 + l15;
  a0s[(((qb * 8 + m) * 8 + ks) * 64 + lane) * 8 + off] = bf16_rne(v);
}

// ---------------------------------------------------------------- K1: coarse bf16 distance, per-(q,tile) min
// key(q,n) = ||cb_n||^2 - 2 c_q . cb_n  (per-q ||c||^2 dropped; argmin unchanged)
// v2: one block per n-tile, ALL 512 queries computed via internal qb loop.
//  - B tile staged (fp32->bf16) exactly ONCE -> codebook is a single 512 MB HBM stream
//  - A fragments reloaded per qb from L2-resident a0s (256 KB)
//  - LDS: 512 B row stride + 16B-chunk XOR swizzle (chunk ^= row&7) -> conflict-free
__global__ __launch_bounds__(256, 2) void k_coarse(
    const unsigned short* __restrict__ a0s,
    const float* __restrict__ cb,
    float* __restrict__ tileMin)
{
  __shared__ __align__(16) unsigned short Bsh[128 * 256];  // 65536 B, swizzled
  __shared__ float c2sh[128];
  __shared__ float redf[512 * 2];                          // 4096 B

  const int tid  = threadIdx.x;
  const int lane = tid & 63;
  const int w    = tid >> 6;
  const int quad = lane >> 4;
  const int l15  = lane & 15;

  const int nt = blockIdx.x;
  const int n0 = nt * NB;

  const int wq = (w >> 1) * 64;  // wave q-half within each 128-q chunk
  const int wn = (w & 1) * 64;   // wave n-half

  // ---- stage B tile fp32 -> bf16 LDS (swizzled); fused ||cb||^2 wave-reduction.
  // Each wave loads one full row per iteration (lane == float4 index).
#pragma unroll 8
  for (int j = 0; j < 32; ++j) {
    int f = j * 256 + tid;
    int row = f >> 6;
    int c4  = f & 63;
    int n   = n0 + row;
    float4 v = make_float4(0.f, 0.f, 0.f, 0.f);
    if (n < NROWS) v = *(const float4*)(cb + (size_t)n * CDIM + c4 * 4);
    float sq = v.x * v.x + v.y * v.y + v.z * v.z + v.w * v.w;
    uint2 p; p.x = bfp2(v.x, v.y); p.y = bfp2(v.z, v.w);
    int chunk = (c4 >> 1) ^ (row & 7);
    *(uint2*)((char*)Bsh + row * 512 + chunk * 16 + (c4 & 1) * 8) = p;
#pragma unroll
    for (int s = 32; s; s >>= 1) sq += __shfl_xor(sq, s);
    if (lane == 0) c2sh[row] = (n < NROWS) ? sq : 1e30f;
  }
  __syncthreads();

  float cadd[4];
#pragma unroll
  for (int j2 = 0; j2 < 4; ++j2) cadd[j2] = c2sh[wn + j2 * 16 + l15];

  for (int qb = 0; qb < 4; ++qb) {
    // A fragments for this qb, direct from global (L2-resident), coalesced 16B/lane
    bf16x8 afr[4][8];
    {
      const int mg0 = (w >> 1) * 4;
      const unsigned short* base = a0s + (size_t)(qb * 8 + mg0) * 8 * 64 * 8 + lane * 8;
#pragma unroll
      for (int m = 0; m < 4; ++m)
#pragma unroll
        for (int ks = 0; ks < 8; ++ks)
          afr[m][ks] = *(const bf16x8*)(base + (m * 8 + ks) * 64 * 8);
    }

    f32x4 acc[4][4];
#pragma unroll
    for (int m = 0; m < 4; ++m)
#pragma unroll
      for (int j2 = 0; j2 < 4; ++j2) acc[m][j2] = (f32x4){0.f, 0.f, 0.f, 0.f};

#pragma unroll
    for (int ks = 0; ks < 8; ++ks) {
      bf16x8 b[4];
      const int cbase = ks * 4 + quad;   // 16B-chunk index within a row
#pragma unroll
      for (int j2 = 0; j2 < 4; ++j2) {
        const int row = wn + j2 * 16 + l15;
        b[j2] = *(const bf16x8*)((const char*)Bsh + row * 512 + ((cbase ^ (row & 7)) << 4));
      }
#pragma unroll
      for (int m = 0; m < 4; ++m)
#pragma unroll
        for (int j2 = 0; j2 < 4; ++j2)
          acc[m][j2] = __builtin_amdgcn_mfma_f32_16x16x32_bf16(afr[m][ks], b[j2], acc[m][j2], 0, 0, 0);
    }

    // epilogue: per-q min over this tile's 128 n
#pragma unroll
    for (int m = 0; m < 4; ++m) {
#pragma unroll
      for (int r = 0; r < 4; ++r) {
        float kk = 1e30f;
#pragma unroll
        for (int j2 = 0; j2 < 4; ++j2) kk = fminf(kk, acc[m][j2][r] + cadd[j2]);
#pragma unroll
        for (int s = 1; s < 16; s <<= 1) kk = fminf(kk, __shfl_xor(kk, s));
        if (l15 == 0) redf[(qb * 128 + wq + m * 16 + quad * 4 + r) * 2 + (w & 1)] = kk;
      }
    }
  }
  __syncthreads();

#pragma unroll
  for (int qq = 0; qq < 2; ++qq) {
    int q = qq * 256 + tid;
    tileMin[(size_t)q * NTILES + nt] = fminf(redf[q * 2], redf[q * 2 + 1]);
  }
}

// ---------------------------------------------------------------- K2: exact refine + gather prev
__global__ __launch_bounds__(256) void k_refine(
    const float* __restrict__ codes, const float* __restrict__ cb,
    const float* __restrict__ tileMin, float* __restrict__ prev)
{
#define LCAP 96
  __shared__ float csh[256];
  __shared__ float red[256];
  __shared__ int   list[LCAP];
  __shared__ int   cnt;
  __shared__ double rd[256];
  __shared__ int    rn[256];

  const int q = blockIdx.x;
  const int tid = threadIdx.x;
  csh[tid] = codes[q * CDIM + tid];
  if (tid == 0) cnt = 0;
  const float* tm = tileMin + (size_t)q * NTILES;
  float lm = 1e30f;
  for (int t = tid; t < NTILES; t += 256) lm = fminf(lm, tm[t]);
  red[tid] = lm;
  __syncthreads();
  for (int s = 128; s; s >>= 1) {
    if (tid < s) red[tid] = fminf(red[tid], red[tid + s]);
    __syncthreads();
  }
  const float thresh = red[0] + DELTA;
  for (int t = tid; t < NTILES; t += 256)
    if (tm[t] <= thresh) { int p = atomicAdd(&cnt, 1); if (p < LCAP) list[p] = t; }
  __syncthreads();
  const int nl = min(cnt, LCAP);

  double bestK = 1e300; int bestN = 0x7FFFFFFF;
  for (int li = 0; li < nl; ++li) {
    const int t = list[li];
    const int row = tid >> 1, half = tid & 1;
    const int n = t * NB + row;
    if (n < NROWS) {
      const float* r = cb + (size_t)n * CDIM;
      double dot = 0.0, sq = 0.0;
      for (int u = half * 32; u < half * 32 + 32; ++u) {
        float4 cv = *(const float4*)(r + u * 4);
        dot += (double)cv.x * csh[u*4+0] + (double)cv.y * csh[u*4+1]
             + (double)cv.z * csh[u*4+2] + (double)cv.w * csh[u*4+3];
        sq  += (double)cv.x * cv.x + (double)cv.y * cv.y
             + (double)cv.z * cv.z + (double)cv.w * cv.w;
      }
      dot += __shfl_xor(dot, 1);
      sq  += __shfl_xor(sq, 1);
      double key = sq - 2.0 * dot;
      if (key < bestK || (key == bestK && n < bestN)) { bestK = key; bestN = n; }
    }
  }
  rd[tid] = bestK; rn[tid] = bestN;
  __syncthreads();
  for (int s = 128; s; s >>= 1) {
    if (tid < s) {
      if (rd[tid + s] < rd[tid] || (rd[tid + s] == rd[tid] && rn[tid + s] < rn[tid])) {
        rd[tid] = rd[tid + s]; rn[tid] = rn[tid + s];
      }
    }
    __syncthreads();
  }
  const int nstar = rn[0];
  prev[(size_t)q * CDIM + tid] = cb[(size_t)nstar * CDIM + tid];
}

// ---------------------------------------------------------------- K3: MLP GEMM (up to 3 jobs via blockIdx.z)
struct Job {
  const float* A1; const float* A2; const float* A3;
  const float* W;  const float* bias; float* out;
};

__global__ __launch_bounds__(256) void k_gemm(
    Job j0, Job j1, Job j2, int Kdim, int Ntot, int do_tanh)
{
  __shared__ unsigned short Ash[128 * LDB];
  __shared__ unsigned short Wsh[64 * LDB];
  __shared__ float bsh[64];

  const Job jb = (blockIdx.z == 0) ? j0 : ((blockIdx.z == 1) ? j1 : j2);
  const float* __restrict__ A1 = jb.A1;
  const float* __restrict__ A2 = jb.A2;
  const float* __restrict__ A3 = jb.A3;
  const float* __restrict__ W  = jb.W;

  const int tid  = threadIdx.x;
  const int lane = tid & 63;
  const int w    = tid >> 6;
  const int quad = lane >> 4;
  const int l15  = lane & 15;
  const int q0   = blockIdx.x * 128;
  const int n0   = blockIdx.y * 64;

  if (tid < 64) bsh[tid] = jb.bias[n0 + tid];

  f32x4 acc[2][4];
#pragma unroll
  for (int m = 0; m < 2; ++m)
#pragma unroll
    for (int j = 0; j < 4; ++j) acc[m][j] = (f32x4){0.f, 0.f, 0.f, 0.f};

  for (int kc = 0; kc < Kdim; kc += 256) {
    __syncthreads();
#pragma unroll 4
    for (int it = 0; it < 32; ++it) {
      int i = it * 256 + tid;
      int row = i >> 6, c4 = i & 63;
      size_t gi = (size_t)(q0 + row) * Kdim + kc + c4 * 4;
      float4 v = *(const float4*)(A1 + gi);
      if (A2) { float4 u = *(const float4*)(A2 + gi); v.x += u.x; v.y += u.y; v.z += u.z; v.w += u.w; }
      if (A3) { float4 u = *(const float4*)(A3 + gi); v.x += u.x; v.y += u.y; v.z += u.z; v.w += u.w; }
      uint2 p; p.x = bfp2(v.x, v.y); p.y = bfp2(v.z, v.w);
      *(uint2*)&Ash[row * LDB + c4 * 4] = p;
    }
#pragma unroll 4
    for (int it = 0; it < 16; ++it) {
      int i = it * 256 + tid;
      int row = i >> 6, c4 = i & 63;
      size_t gi = (size_t)(n0 + row) * Kdim + kc + c4 * 4;
      float4 v = *(const float4*)(W + gi);
      uint2 p; p.x = bfp2(v.x, v.y); p.y = bfp2(v.z, v.w);
      *(uint2*)&Wsh[row * LDB + c4 * 4] = p;
    }
    __syncthreads();
#pragma unroll
    for (int ks = 0; ks < 8; ++ks) {
      const int kb = ks * 32 + quad * 8;
      bf16x8 a[2], b[4];
#pragma unroll
      for (int m = 0; m < 2; ++m)
        a[m] = *(const bf16x8*)&Ash[(w * 32 + m * 16 + l15) * LDB + kb];
#pragma unroll
      for (int j = 0; j < 4; ++j)
        b[j] = *(const bf16x8*)&Wsh[(j * 16 + l15) * LDB + kb];
#pragma unroll
      for (int m = 0; m < 2; ++m)
#pragma unroll
        for (int j = 0; j < 4; ++j)
          acc[m][j] = __builtin_amdgcn_mfma_f32_16x16x32_bf16(a[m], b[j], acc[m][j], 0, 0, 0);
    }
  }

#pragma unroll
  for (int m = 0; m < 2; ++m)
#pragma unroll
    for (int j = 0; j < 4; ++j)
#pragma unroll
      for (int r = 0; r < 4; ++r) {
        int q = q0 + w * 32 + m * 16 + quad * 4 + r;
        int n = j * 16 + l15;
        float v = acc[m][j][r] + bsh[n];
        if (do_tanh) v = tanhf(v);
        jb.out[(size_t)q * Ntot + n0 + n] = v;
      }
}

// ---------------------------------------------------------------- launch
extern "C" void kernel_launch(void* const* d_in, const int* in_sizes, int n_in,
                              void* d_out, int out_size, void* d_ws, size_t ws_size,
                              hipStream_t stream) {
  const float* codes = (const float*)d_in[0];
  const float* cb    = (const float*)d_in[1];
  const float* w_in  = (const float*)d_in[2];
  const float* b_in  = (const float*)d_in[3];
  const float* w_h1  = (const float*)d_in[4];
  const float* b_h1  = (const float*)d_in[5];
  const float* w_s2  = (const float*)d_in[6];
  const float* b_s2  = (const float*)d_in[7];
  const float* w_s3  = (const float*)d_in[8];
  const float* b_s3  = (const float*)d_in[9];
  const float* w_h2  = (const float*)d_in[10];
  const float* b_h2  = (const float*)d_in[11];
  const float* w_s1o = (const float*)d_in[12];
  const float* b_s1o = (const float*)d_in[13];
  const float* w_s2o = (const float*)d_in[14];
  const float* b_s2o = (const float*)d_in[15];
  const float* w_h3  = (const float*)d_in[16];
  const float* b_h3  = (const float*)d_in[17];
  const float* w_mu  = (const float*)d_in[18];
  const float* b_mu  = (const float*)d_in[19];
  const float* w_s   = (const float*)d_in[20];
  const float* b_s   = (const float*)d_in[21];
  float* out = (float*)d_out;

  char* ws = (char*)d_ws;
  unsigned short* a0s = (unsigned short*)ws;                     // 262,144 B
  float* tileMin = (float*)(ws + 262144);                        // 8,001,536 B
  float* prev    = (float*)(ws + 262144 + 8001536);              // 524,288 B
  float* acts    = (float*)(ws + 262144 + 8001536 + 524288);     // 8 x 2 MiB
  const int ACT = 512 * 1024;
  float* act_i  = acts + 0 * ACT;
  float* act_h1 = acts + 1 * ACT;
  float* act_s2 = acts + 2 * ACT;
  float* act_s3 = acts + 3 * ACT;
  float* act_h2 = acts + 4 * ACT;
  float* act_o1 = acts + 5 * ACT;
  float* act_o2 = acts + 6 * ACT;
  float* act_o3 = acts + 7 * ACT;

  hipLaunchKernelGGL(k_prep,   dim3(512),    dim3(256), 0, stream, codes, a0s);
  hipLaunchKernelGGL(k_coarse, dim3(NTILES), dim3(256), 0, stream, a0s, cb, tileMin);
  hipLaunchKernelGGL(k_refine, dim3(512),    dim3(256), 0, stream, codes, cb, tileMin, prev);

  const float* NUL = nullptr;
  Job in_j  = { prev,   NUL,    NUL,    w_in,  b_in,  act_i  };
  Job h1_j  = { act_i,  NUL,    NUL,    w_h1,  b_h1,  act_h1 };
  Job s2_j  = { act_h1, NUL,    NUL,    w_s2,  b_s2,  act_s2 };
  Job s3_j  = { act_h1, NUL,    NUL,    w_s3,  b_s3,  act_s3 };
  Job o1_j  = { act_h1, NUL,    NUL,    w_s1o, b_s1o, act_o1 };
  Job h2_j  = { act_h1, act_s2, NUL,    w_h2,  b_h2,  act_h2 };
  Job o2_j  = { act_h2, NUL,    NUL,    w_s2o, b_s2o, act_o2 };
  Job o3_j  = { act_h2, act_s3, NUL,    w_h3,  b_h3,  act_o3 };
  Job mu_j  = { act_o1, act_o2, act_o3, w_mu,  b_mu,  out            };
  Job ls_j  = { act_o1, act_o2, act_o3, w_s,   b_s,   out + 131072   };

  hipLaunchKernelGGL(k_gemm, dim3(4, 16, 1), dim3(256), 0, stream, in_j, in_j, in_j, 256,  1024, 1);
  hipLaunchKernelGGL(k_gemm, dim3(4, 16, 1), dim3(256), 0, stream, h1_j, h1_j, h1_j, 1024, 1024, 1);
  hipLaunchKernelGGL(k_gemm, dim3(4, 16, 3), dim3(256), 0, stream, s2_j, s3_j, o1_j, 1024, 1024, 1);
  hipLaunchKernelGGL(k_gemm, dim3(4, 16, 1), dim3(256), 0, stream, h2_j, h2_j, h2_j, 1024, 1024, 1);
  hipLaunchKernelGGL(k_gemm, dim3(4, 16, 2), dim3(256), 0, stream, o2_j, o3_j, o3_j, 1024, 1024, 1);
  hipLaunchKernelGGL(k_gemm, dim3(4, 4, 2),  dim3(256), 0, stream, mu_j, ls_j, ls_j, 1024, 256,  0);
}

// Round 2
// 1331.516 us; speedup vs baseline: 1.3570x; 1.0336x over previous
//
#include <hip/hip_runtime.h>
#include <math.h>

// Problem constants
#define QTOT   512
#define CDIM   256
#define HDIM   1024
#define NROWS  500000
#define NB     128
#define NTILES ((NROWS + NB - 1) / NB)   // 3907
#define NPADR  (NTILES * NB)             // 500096 padded rows
#define LDB    264                       // bf16 row stride in LDS (k_gemm + fallback)
#define DELTA  2.0f

// chunking of the codebook for the conv+coarse passes
#define C0_T   1954                      // tiles in chunk 0
#define C1_T   (NTILES - C0_T)           // 1953
#define C0_R   (C0_T * NB)               // 250112 rows
#define C1_R   (C1_T * NB)               // 249984 rows (includes pad tail)

typedef short bf16x8 __attribute__((ext_vector_type(8)));
typedef float f32x4  __attribute__((ext_vector_type(4)));
typedef unsigned int u32;

__device__ __forceinline__ unsigned short bf16_rne(float f) {
  unsigned u = __float_as_uint(f);
  u += 0x7FFFu + ((u >> 16) & 1u);
  return (unsigned short)(u >> 16);
}
__device__ __forceinline__ unsigned bfp2(float a, float b) {
  return (unsigned)bf16_rne(a) | ((unsigned)bf16_rne(b) << 16);
}

// async global->LDS, 16B per lane; lds dest must be wave-uniform base (lane*16 implicit)
__device__ __forceinline__ void gld16(const void* g, void* l) {
  __builtin_amdgcn_global_load_lds((const __attribute__((address_space(1))) u32*)g,
                                   (__attribute__((address_space(3))) u32*)l, 16, 0, 0);
}

// DPP reductions within 16-lane rows (all VALU-speed, no LDS pipe)
#define FMIN_DPP(x, ctrl) do { \
    int _t = __builtin_amdgcn_update_dpp(__float_as_int(x), __float_as_int(x), (ctrl), 0xF, 0xF, false); \
    x = fminf(x, __int_as_float(_t)); } while (0)
#define FADD_DPP(x, ctrl) do { \
    int _t = __builtin_amdgcn_update_dpp(__float_as_int(x), __float_as_int(x), (ctrl), 0xF, 0xF, false); \
    x += __int_as_float(_t); } while (0)

// ---------------------------------------------------------------- K0: codes -> bf16(-2c), MFMA-frag swizzled
// frag layout: [qb(4)][m(8)][ks(8)][lane(64)][8 bf16]; lane = quad*16 + l15
// lane l of frag (qb,m,ks) holds A[q = qb*128 + m*16 + (l&15)][k = ks*32 + (l>>4)*8 + off]
__global__ void k_prep(const float* __restrict__ codes, unsigned short* __restrict__ a0s) {
  int q = blockIdx.x, k = threadIdx.x;
  float v = -2.0f * codes[q * CDIM + k];
  int qb = q >> 7, row = q & 127, m = row >> 4, l15 = row & 15;
  int ks = k >> 5, kin = k & 31, quad = kin >> 3, off = kin & 7;
  int lane = quad * 16 + l15;
  a0s[(((qb * 8 + m) * 8 + ks) * 64 + lane) * 8 + off] = bf16_rne(v);
}

// ---------------------------------------------------------------- K_conv: fp32 codebook chunk -> bf16 rows + fp32 ||cb||^2
// linear bf16 layout: cbh[r][256], row stride 512 B. pad rows -> zeros, c2 = 1e30.
__global__ __launch_bounds__(256) void k_conv(
    const float* __restrict__ cb, unsigned short* __restrict__ cbh,
    float* __restrict__ c2, int row0, int nrows)
{
  const int lane = threadIdx.x & 63;
  const int wid  = (blockIdx.x * 256 + threadIdx.x) >> 6;
  const int nw   = (gridDim.x * 256) >> 6;
  for (int r = wid; r < nrows; r += nw) {
    const int gr = row0 + r;
    float4 v = make_float4(0.f, 0.f, 0.f, 0.f);
    if (gr < NROWS) v = *(const float4*)(cb + (size_t)gr * CDIM + lane * 4);
    float sq = v.x * v.x + v.y * v.y + v.z * v.z + v.w * v.w;
    // 64-lane sum: 4 DPP stages within 16-lane rows, then 2 cross-row shuffles
    FADD_DPP(sq, 0xB1);   // quad_perm xor1
    FADD_DPP(sq, 0x4E);   // quad_perm xor2
    FADD_DPP(sq, 0x124);  // row_ror:4
    FADD_DPP(sq, 0x128);  // row_ror:8
    sq += __shfl_xor(sq, 16);
    sq += __shfl_xor(sq, 32);
    uint2 p; p.x = bfp2(v.x, v.y); p.y = bfp2(v.z, v.w);
    *(uint2*)((char*)cbh + (size_t)r * 512 + lane * 8) = p;
    if (lane == 0) c2[r] = (gr < NROWS) ? sq : 1e30f;
  }
}

// ---------------------------------------------------------------- K1 v3: coarse bf16 distance, per-(q,tile) min
// one block per n-tile (chunked); all 512 q via qb loop.
//  - B tile staged via global_load_lds (16B), linear LDS dest, inverse-swizzled SOURCE
//  - ds_read side applies chunk ^= row&7 XOR (conflict-free: 8 lanes / 4-bank group)
//  - A fragments: explicit 2-deep ks prefetch pipeline (48 VGPR rolling buffer)
//  - epilogue l15-reduction via DPP min (no ds_bpermute chains)
__global__ __launch_bounds__(256, 2) void k_coarse(
    const unsigned short* __restrict__ a0s,
    const unsigned short* __restrict__ cbh,
    const float* __restrict__ c2arr,
    float* __restrict__ tileMin, int nt0)
{
  __shared__ __align__(16) unsigned short Bsh[128 * 256];  // 65536 B, content-swizzled
  __shared__ float c2sh[128];
  __shared__ float redf[512 * 2];

  const int tid  = threadIdx.x;
  const int lane = tid & 63;
  const int w    = tid >> 6;
  const int quad = lane >> 4;
  const int l15  = lane & 15;

  const int ntl  = blockIdx.x;        // chunk-local tile
  const int ntg  = nt0 + ntl;         // global tile

  const int wq = (w >> 1) * 64;       // wave q-half within each 128-q chunk
  const int wn = (w & 1) * 64;        // wave n-half

  // ---- stage B tile: 64 x global_load_lds, 1 KB each. LDS[row][cS] = cbh[row][cS ^ (row&7)]
  {
    const char* tbase = (const char*)cbh + (size_t)ntl * 65536;
#pragma unroll
    for (int i2 = 0; i2 < 16; ++i2) {
      const int i   = w * 16 + i2;
      const int row = 2 * i + (lane >> 5);
      const int cS  = lane & 31;
      gld16(tbase + (size_t)row * 512 + ((cS ^ (row & 7)) << 4),
            (char*)Bsh + i * 1024);
    }
  }
  if (tid < 128) c2sh[tid] = c2arr[ntl * NB + tid];
  __syncthreads();   // drains vmcnt -> tile + c2 ready

  float cadd[4];
#pragma unroll
  for (int j2 = 0; j2 < 4; ++j2) cadd[j2] = c2sh[wn + j2 * 16 + l15];

  for (int qb = 0; qb < 4; ++qb) {
    const unsigned short* abase = a0s + (size_t)(qb * 8 + (w >> 1) * 4) * 4096 + lane * 8;

    f32x4 acc[4][4];
#pragma unroll
    for (int m = 0; m < 4; ++m)
#pragma unroll
      for (int j2 = 0; j2 < 4; ++j2) acc[m][j2] = (f32x4){0.f, 0.f, 0.f, 0.f};

    // 2-deep rolling A-fragment prefetch: slot = ks % 3 (compile-time after unroll)
    bf16x8 apf[3][4];
#pragma unroll
    for (int m = 0; m < 4; ++m) apf[0][m] = *(const bf16x8*)(abase + (m * 8 + 0) * 512);
#pragma unroll
    for (int m = 0; m < 4; ++m) apf[1][m] = *(const bf16x8*)(abase + (m * 8 + 1) * 512);

#pragma unroll
    for (int ks = 0; ks < 8; ++ks) {
      if (ks + 2 < 8) {
#pragma unroll
        for (int m = 0; m < 4; ++m)
          apf[(ks + 2) % 3][m] = *(const bf16x8*)(abase + (m * 8 + ks + 2) * 512);
      }
      bf16x8 b[4];
#pragma unroll
      for (int j2 = 0; j2 < 4; ++j2) {
        const int row = wn + j2 * 16 + l15;
        b[j2] = *(const bf16x8*)((const char*)Bsh + row * 512 + (((ks * 4 + quad) ^ (row & 7)) << 4));
      }
#pragma unroll
      for (int m = 0; m < 4; ++m)
#pragma unroll
        for (int j2 = 0; j2 < 4; ++j2)
          acc[m][j2] = __builtin_amdgcn_mfma_f32_16x16x32_bf16(apf[ks % 3][m], b[j2], acc[m][j2], 0, 0, 0);
    }

    // epilogue: per-q min over the tile's 128 n; l15-reduction via DPP
#pragma unroll
    for (int m = 0; m < 4; ++m) {
#pragma unroll
      for (int r = 0; r < 4; ++r) {
        float kk = fminf(fminf(acc[m][0][r] + cadd[0], acc[m][1][r] + cadd[1]),
                         fminf(acc[m][2][r] + cadd[2], acc[m][3][r] + cadd[3]));
        FMIN_DPP(kk, 0xB1);   // xor1
        FMIN_DPP(kk, 0x4E);   // xor2
        FMIN_DPP(kk, 0x124);  // ror4
        FMIN_DPP(kk, 0x128);  // ror8
        if (l15 == 0) redf[(qb * 128 + wq + m * 16 + quad * 4 + r) * 2 + (w & 1)] = kk;
      }
    }
  }
  __syncthreads();

#pragma unroll
  for (int qq = 0; qq < 2; ++qq) {
    int q = qq * 256 + tid;
    tileMin[(size_t)q * NTILES + ntg] = fminf(redf[q * 2], redf[q * 2 + 1]);
  }
}

// ---------------------------------------------------------------- K1 fallback (round-1 version, used if ws too small)
__global__ __launch_bounds__(256, 2) void k_coarse_fb(
    const unsigned short* __restrict__ a0s,
    const float* __restrict__ cb,
    float* __restrict__ tileMin)
{
  __shared__ __align__(16) unsigned short Bsh[128 * 256];
  __shared__ float c2sh[128];
  __shared__ float redf[512 * 2];

  const int tid  = threadIdx.x;
  const int lane = tid & 63;
  const int w    = tid >> 6;
  const int quad = lane >> 4;
  const int l15  = lane & 15;

  const int nt = blockIdx.x;
  const int n0 = nt * NB;

  const int wq = (w >> 1) * 64;
  const int wn = (w & 1) * 64;

#pragma unroll 8
  for (int j = 0; j < 32; ++j) {
    int f = j * 256 + tid;
    int row = f >> 6;
    int c4  = f & 63;
    int n   = n0 + row;
    float4 v = make_float4(0.f, 0.f, 0.f, 0.f);
    if (n < NROWS) v = *(const float4*)(cb + (size_t)n * CDIM + c4 * 4);
    float sq = v.x * v.x + v.y * v.y + v.z * v.z + v.w * v.w;
    uint2 p; p.x = bfp2(v.x, v.y); p.y = bfp2(v.z, v.w);
    int chunk = (c4 >> 1) ^ (row & 7);
    *(uint2*)((char*)Bsh + row * 512 + chunk * 16 + (c4 & 1) * 8) = p;
#pragma unroll
    for (int s = 32; s; s >>= 1) sq += __shfl_xor(sq, s);
    if (lane == 0) c2sh[row] = (n < NROWS) ? sq : 1e30f;
  }
  __syncthreads();

  float cadd[4];
#pragma unroll
  for (int j2 = 0; j2 < 4; ++j2) cadd[j2] = c2sh[wn + j2 * 16 + l15];

  for (int qb = 0; qb < 4; ++qb) {
    bf16x8 afr[4][8];
    {
      const int mg0 = (w >> 1) * 4;
      const unsigned short* base = a0s + (size_t)(qb * 8 + mg0) * 8 * 64 * 8 + lane * 8;
#pragma unroll
      for (int m = 0; m < 4; ++m)
#pragma unroll
        for (int ks = 0; ks < 8; ++ks)
          afr[m][ks] = *(const bf16x8*)(base + (m * 8 + ks) * 64 * 8);
    }
    f32x4 acc[4][4];
#pragma unroll
    for (int m = 0; m < 4; ++m)
#pragma unroll
      for (int j2 = 0; j2 < 4; ++j2) acc[m][j2] = (f32x4){0.f, 0.f, 0.f, 0.f};
#pragma unroll
    for (int ks = 0; ks < 8; ++ks) {
      bf16x8 b[4];
      const int cbase = ks * 4 + quad;
#pragma unroll
      for (int j2 = 0; j2 < 4; ++j2) {
        const int row = wn + j2 * 16 + l15;
        b[j2] = *(const bf16x8*)((const char*)Bsh + row * 512 + ((cbase ^ (row & 7)) << 4));
      }
#pragma unroll
      for (int m = 0; m < 4; ++m)
#pragma unroll
        for (int j2 = 0; j2 < 4; ++j2)
          acc[m][j2] = __builtin_amdgcn_mfma_f32_16x16x32_bf16(afr[m][ks], b[j2], acc[m][j2], 0, 0, 0);
    }
#pragma unroll
    for (int m = 0; m < 4; ++m) {
#pragma unroll
      for (int r = 0; r < 4; ++r) {
        float kk = 1e30f;
#pragma unroll
        for (int j2 = 0; j2 < 4; ++j2) kk = fminf(kk, acc[m][j2][r] + cadd[j2]);
#pragma unroll
        for (int s = 1; s < 16; s <<= 1) kk = fminf(kk, __shfl_xor(kk, s));
        if (l15 == 0) redf[(qb * 128 + wq + m * 16 + quad * 4 + r) * 2 + (w & 1)] = kk;
      }
    }
  }
  __syncthreads();

#pragma unroll
  for (int qq = 0; qq < 2; ++qq) {
    int q = qq * 256 + tid;
    tileMin[(size_t)q * NTILES + nt] = fminf(redf[q * 2], redf[q * 2 + 1]);
  }
}

// ---------------------------------------------------------------- K2: exact refine + gather prev
__global__ __launch_bounds__(256) void k_refine(
    const float* __restrict__ codes, const float* __restrict__ cb,
    const float* __restrict__ tileMin, float* __restrict__ prev)
{
#define LCAP 96
  __shared__ float csh[256];
  __shared__ float red[256];
  __shared__ int   list[LCAP];
  __shared__ int   cnt;
  __shared__ double rd[256];
  __shared__ int    rn[256];

  const int q = blockIdx.x;
  const int tid = threadIdx.x;
  csh[tid] = codes[q * CDIM + tid];
  if (tid == 0) cnt = 0;
  const float* tm = tileMin + (size_t)q * NTILES;
  float lm = 1e30f;
  for (int t = tid; t < NTILES; t += 256) lm = fminf(lm, tm[t]);
  red[tid] = lm;
  __syncthreads();
  for (int s = 128; s; s >>= 1) {
    if (tid < s) red[tid] = fminf(red[tid], red[tid + s]);
    __syncthreads();
  }
  const float thresh = red[0] + DELTA;
  for (int t = tid; t < NTILES; t += 256)
    if (tm[t] <= thresh) { int p = atomicAdd(&cnt, 1); if (p < LCAP) list[p] = t; }
  __syncthreads();
  const int nl = min(cnt, LCAP);

  double bestK = 1e300; int bestN = 0x7FFFFFFF;
  for (int li = 0; li < nl; ++li) {
    const int t = list[li];
    const int row = tid >> 1, half = tid & 1;
    const int n = t * NB + row;
    if (n < NROWS) {
      const float* r = cb + (size_t)n * CDIM;
      double dot = 0.0, sq = 0.0;
      for (int u = half * 32; u < half * 32 + 32; ++u) {
        float4 cv = *(const float4*)(r + u * 4);
        dot += (double)cv.x * csh[u*4+0] + (double)cv.y * csh[u*4+1]
             + (double)cv.z * csh[u*4+2] + (double)cv.w * csh[u*4+3];
        sq  += (double)cv.x * cv.x + (double)cv.y * cv.y
             + (double)cv.z * cv.z + (double)cv.w * cv.w;
      }
      dot += __shfl_xor(dot, 1);
      sq  += __shfl_xor(sq, 1);
      double key = sq - 2.0 * dot;
      if (key < bestK || (key == bestK && n < bestN)) { bestK = key; bestN = n; }
    }
  }
  rd[tid] = bestK; rn[tid] = bestN;
  __syncthreads();
  for (int s = 128; s; s >>= 1) {
    if (tid < s) {
      if (rd[tid + s] < rd[tid] || (rd[tid + s] == rd[tid] && rn[tid + s] < rn[tid])) {
        rd[tid] = rd[tid + s]; rn[tid] = rn[tid + s];
      }
    }
    __syncthreads();
  }
  const int nstar = rn[0];
  prev[(size_t)q * CDIM + tid] = cb[(size_t)nstar * CDIM + tid];
}

// ---------------------------------------------------------------- K3: MLP GEMM (up to 3 jobs via blockIdx.z)
struct Job {
  const float* A1; const float* A2; const float* A3;
  const float* W;  const float* bias; float* out;
};

__global__ __launch_bounds__(256) void k_gemm(
    Job j0, Job j1, Job j2, int Kdim, int Ntot, int do_tanh)
{
  __shared__ unsigned short Ash[128 * LDB];
  __shared__ unsigned short Wsh[64 * LDB];
  __shared__ float bsh[64];

  const Job jb = (blockIdx.z == 0) ? j0 : ((blockIdx.z == 1) ? j1 : j2);
  const float* __restrict__ A1 = jb.A1;
  const float* __restrict__ A2 = jb.A2;
  const float* __restrict__ A3 = jb.A3;
  const float* __restrict__ W  = jb.W;

  const int tid  = threadIdx.x;
  const int lane = tid & 63;
  const int w    = tid >> 6;
  const int quad = lane >> 4;
  const int l15  = lane & 15;
  const int q0   = blockIdx.x * 128;
  const int n0   = blockIdx.y * 64;

  if (tid < 64) bsh[tid] = jb.bias[n0 + tid];

  f32x4 acc[2][4];
#pragma unroll
  for (int m = 0; m < 2; ++m)
#pragma unroll
    for (int j = 0; j < 4; ++j) acc[m][j] = (f32x4){0.f, 0.f, 0.f, 0.f};

  for (int kc = 0; kc < Kdim; kc += 256) {
    __syncthreads();
#pragma unroll 4
    for (int it = 0; it < 32; ++it) {
      int i = it * 256 + tid;
      int row = i >> 6, c4 = i & 63;
      size_t gi = (size_t)(q0 + row) * Kdim + kc + c4 * 4;
      float4 v = *(const float4*)(A1 + gi);
      if (A2) { float4 u = *(const float4*)(A2 + gi); v.x += u.x; v.y += u.y; v.z += u.z; v.w += u.w; }
      if (A3) { float4 u = *(const float4*)(A3 + gi); v.x += u.x; v.y += u.y; v.z += u.z; v.w += u.w; }
      uint2 p; p.x = bfp2(v.x, v.y); p.y = bfp2(v.z, v.w);
      *(uint2*)&Ash[row * LDB + c4 * 4] = p;
    }
#pragma unroll 4
    for (int it = 0; it < 16; ++it) {
      int i = it * 256 + tid;
      int row = i >> 6, c4 = i & 63;
      size_t gi = (size_t)(n0 + row) * Kdim + kc + c4 * 4;
      float4 v = *(const float4*)(W + gi);
      uint2 p; p.x = bfp2(v.x, v.y); p.y = bfp2(v.z, v.w);
      *(uint2*)&Wsh[row * LDB + c4 * 4] = p;
    }
    __syncthreads();
#pragma unroll
    for (int ks = 0; ks < 8; ++ks) {
      const int kb = ks * 32 + quad * 8;
      bf16x8 a[2], b[4];
#pragma unroll
      for (int m = 0; m < 2; ++m)
        a[m] = *(const bf16x8*)&Ash[(w * 32 + m * 16 + l15) * LDB + kb];
#pragma unroll
      for (int j = 0; j < 4; ++j)
        b[j] = *(const bf16x8*)&Wsh[(j * 16 + l15) * LDB + kb];
#pragma unroll
      for (int m = 0; m < 2; ++m)
#pragma unroll
        for (int j = 0; j < 4; ++j)
          acc[m][j] = __builtin_amdgcn_mfma_f32_16x16x32_bf16(a[m], b[j], acc[m][j], 0, 0, 0);
    }
  }

#pragma unroll
  for (int m = 0; m < 2; ++m)
#pragma unroll
    for (int j = 0; j < 4; ++j)
#pragma unroll
      for (int r = 0; r < 4; ++r) {
        int q = q0 + w * 32 + m * 16 + quad * 4 + r;
        int n = j * 16 + l15;
        float v = acc[m][j][r] + bsh[n];
        if (do_tanh) v = tanhf(v);
        jb.out[(size_t)q * Ntot + n0 + n] = v;
      }
}

// ---------------------------------------------------------------- launch
extern "C" void kernel_launch(void* const* d_in, const int* in_sizes, int n_in,
                              void* d_out, int out_size, void* d_ws, size_t ws_size,
                              hipStream_t stream) {
  const float* codes = (const float*)d_in[0];
  const float* cb    = (const float*)d_in[1];
  const float* w_in  = (const float*)d_in[2];
  const float* b_in  = (const float*)d_in[3];
  const float* w_h1  = (const float*)d_in[4];
  const float* b_h1  = (const float*)d_in[5];
  const float* w_s2  = (const float*)d_in[6];
  const float* b_s2  = (const float*)d_in[7];
  const float* w_s3  = (const float*)d_in[8];
  const float* b_s3  = (const float*)d_in[9];
  const float* w_h2  = (const float*)d_in[10];
  const float* b_h2  = (const float*)d_in[11];
  const float* w_s1o = (const float*)d_in[12];
  const float* b_s1o = (const float*)d_in[13];
  const float* w_s2o = (const float*)d_in[14];
  const float* b_s2o = (const float*)d_in[15];
  const float* w_h3  = (const float*)d_in[16];
  const float* b_h3  = (const float*)d_in[17];
  const float* w_mu  = (const float*)d_in[18];
  const float* b_mu  = (const float*)d_in[19];
  const float* w_s   = (const float*)d_in[20];
  const float* b_s   = (const float*)d_in[21];
  float* out = (float*)d_out;

  char* ws = (char*)d_ws;
  unsigned short* a0s = (unsigned short*)ws;                     // 262,144 B
  float* tileMin = (float*)(ws + 262144);                        // 8,001,536 B
  float* prev    = (float*)(ws + 262144 + 8001536);              // 524,288 B
  float* acts    = (float*)(ws + 262144 + 8001536 + 524288);     // 8 x 2 MiB
  const int ACT = 512 * 1024;
  float* act_i  = acts + 0 * ACT;
  float* act_h1 = acts + 1 * ACT;
  float* act_s2 = acts + 2 * ACT;
  float* act_s3 = acts + 3 * ACT;
  float* act_h2 = acts + 4 * ACT;
  float* act_o1 = acts + 5 * ACT;
  float* act_o2 = acts + 6 * ACT;
  float* act_o3 = acts + 7 * ACT;

  // bf16 codebook chunk buffer + c2 after the legacy 25.5 MB region
  const size_t CBH_OFF = 262144 + 8001536 + 524288 + 16777216;   // 25,565,184
  const size_t CBH_SZ  = (size_t)C0_R * 512;                     // 128,057,344 (chunk max)
  const size_t C2_OFF  = CBH_OFF + CBH_SZ;
  const size_t NEED    = C2_OFF + (size_t)C0_R * 4;              // ~155 MB
  unsigned short* cbh = (unsigned short*)(ws + CBH_OFF);
  float* c2buf        = (float*)(ws + C2_OFF);

  hipLaunchKernelGGL(k_prep, dim3(512), dim3(256), 0, stream, codes, a0s);

  if (ws_size >= NEED) {
    // chunk 0
    hipLaunchKernelGGL(k_conv,   dim3(2048), dim3(256), 0, stream, cb, cbh, c2buf, 0, C0_R);
    hipLaunchKernelGGL(k_coarse, dim3(C0_T), dim3(256), 0, stream, a0s, cbh, c2buf, tileMin, 0);
    // chunk 1
    hipLaunchKernelGGL(k_conv,   dim3(2048), dim3(256), 0, stream, cb, cbh, c2buf, C0_R, C1_R);
    hipLaunchKernelGGL(k_coarse, dim3(C1_T), dim3(256), 0, stream, a0s, cbh, c2buf, tileMin, C0_T);
  } else {
    hipLaunchKernelGGL(k_coarse_fb, dim3(NTILES), dim3(256), 0, stream, a0s, cb, tileMin);
  }

  hipLaunchKernelGGL(k_refine, dim3(512), dim3(256), 0, stream, codes, cb, tileMin, prev);

  const float* NUL = nullptr;
  Job in_j  = { prev,   NUL,    NUL,    w_in,  b_in,  act_i  };
  Job h1_j  = { act_i,  NUL,    NUL,    w_h1,  b_h1,  act_h1 };
  Job s2_j  = { act_h1, NUL,    NUL,    w_s2,  b_s2,  act_s2 };
  Job s3_j  = { act_h1, NUL,    NUL,    w_s3,  b_s3,  act_s3 };
  Job o1_j  = { act_h1, NUL,    NUL,    w_s1o, b_s1o, act_o1 };
  Job h2_j  = { act_h1, act_s2, NUL,    w_h2,  b_h2,  act_h2 };
  Job o2_j  = { act_h2, NUL,    NUL,    w_s2o, b_s2o, act_o2 };
  Job o3_j  = { act_h2, act_s3, NUL,    w_h3,  b_h3,  act_o3 };
  Job mu_j  = { act_o1, act_o2, act_o3, w_mu,  b_mu,  out            };
  Job ls_j  = { act_o1, act_o2, act_o3, w_s,   b_s,   out + 131072   };

  hipLaunchKernelGGL(k_gemm, dim3(4, 16, 1), dim3(256), 0, stream, in_j, in_j, in_j, 256,  1024, 1);
  hipLaunchKernelGGL(k_gemm, dim3(4, 16, 1), dim3(256), 0, stream, h1_j, h1_j, h1_j, 1024, 1024, 1);
  hipLaunchKernelGGL(k_gemm, dim3(4, 16, 3), dim3(256), 0, stream, s2_j, s3_j, o1_j, 1024, 1024, 1);
  hipLaunchKernelGGL(k_gemm, dim3(4, 16, 1), dim3(256), 0, stream, h2_j, h2_j, h2_j, 1024, 1024, 1);
  hipLaunchKernelGGL(k_gemm, dim3(4, 16, 2), dim3(256), 0, stream, o2_j, o3_j, o3_j, 1024, 1024, 1);
  hipLaunchKernelGGL(k_gemm, dim3(4, 4, 2),  dim3(256), 0, stream, mu_j, ls_j, ls_j, 1024, 256,  0);
}